// Round 8
// baseline (376.725 us; speedup 1.0000x reference)
//
#include <hip/hip_runtime.h>
#include <hip/hip_bf16.h>
#include <math.h>

// Problem constants: B=2, C=128, T=512, F=64 -> N=B*F=128 sequences, NT=65536 rows.
// GRU: G=4 groups, D=32, 3D=96. MHA: H=4 heads, Dh=32, window=100.
// Workspace layout (needs ~100.8 MB):
//   seq  fp32 [65536][128]  @ 0          (33,554,432 B)  residual stream
//   tmpb bf16 [65536][128]  @ 33554432   (16,777,216 B)  ln1/ln2/attn-out
//   big  bf16 [65536][384]  @ 50331648   (50,331,648 B)  xp (grouped: [(n,t,g)][96]) then qkv
//   wbuf bf16 weights       @ 100663296  (~137 KB)

typedef __attribute__((ext_vector_type(8))) short short8;
typedef __attribute__((ext_vector_type(4))) float f32x4;
typedef __attribute__((ext_vector_type(2))) float f32x2;

__device__ __forceinline__ float bflo(unsigned int u) { return __uint_as_float(u << 16); }
__device__ __forceinline__ float bfhi(unsigned int u) { return __uint_as_float(u & 0xffff0000u); }
__device__ __forceinline__ float bf2f(unsigned short u) { return __uint_as_float(((unsigned int)u) << 16); }
__device__ __forceinline__ unsigned short f2bf(float f) {
  __hip_bfloat16 h = __float2bfloat16(f);
  return *reinterpret_cast<unsigned short*>(&h);
}

// global -> LDS hardware DMA, 16 B per lane. LDS dest = uniform base + lane*16; global
// source is per-lane (this is how we choose the LDS flattening).
typedef __attribute__((address_space(1))) const unsigned int uint_g;
typedef __attribute__((address_space(3))) unsigned int uint_l;
__device__ __forceinline__ void glds16(const void* g, void* l) {
  __builtin_amdgcn_global_load_lds((uint_g*)g, (uint_l*)l, 16, 0, 0);
}

// DPP XOR-mask lane shuffle on a packed f32x2 (both components). CTRL is a compile-time
// DPP control: 0xB1 = quad_perm[1,0,3,2] (xor1), 0x1B = quad_perm[3,2,1,0] (xor3),
// 0x141 = row_half_mirror (xor7), 0x140 = row_mirror (xor15). All are direction-symmetric
// patterns — no rotate-direction ambiguity.
template <int CTRL>
__device__ __forceinline__ f32x2 dpp2(f32x2 v) {
  int a = __builtin_amdgcn_mov_dpp(__float_as_int(v.x), CTRL, 0xF, 0xF, false);
  int b = __builtin_amdgcn_mov_dpp(__float_as_int(v.y), CTRL, 0xF, 0xF, false);
  return f32x2{__int_as_float(a), __int_as_float(b)};
}

// ---------------- weight fp32 -> bf16 ----------------
__global__ void cvt_kernel(const float* __restrict__ s, unsigned short* __restrict__ d, int n) {
  int i = blockIdx.x * 256 + threadIdx.x;
  if (i < n) d[i] = f2bf(s[i]);
}

// ---------------- transpose x[B,C,T,F] -> seq[(b*64+f)][t][c] ----------------
__global__ __launch_bounds__(256) void transpose_in_kernel(const float* __restrict__ x, float* __restrict__ seq) {
  __shared__ float tile[128 * 65];
  int b = blockIdx.x >> 9;
  int t = blockIdx.x & 511;
  for (int i = threadIdx.x; i < 128 * 64; i += 256) {
    int c = i >> 6, f = i & 63;
    tile[c * 65 + f] = x[(((size_t)(b * 128 + c)) * 512 + t) * 64 + f];
  }
  __syncthreads();
  for (int i = threadIdx.x; i < 64 * 128; i += 256) {
    int f = i >> 7, c = i & 127;
    seq[(((size_t)(b * 64 + f)) * 512 + t) * 128 + c] = tile[c * 65 + f];
  }
}

__global__ __launch_bounds__(256) void transpose_out_kernel(const float* __restrict__ seq, float* __restrict__ out) {
  __shared__ float tile[128 * 65];
  int b = blockIdx.x >> 9;
  int t = blockIdx.x & 511;
  for (int i = threadIdx.x; i < 64 * 128; i += 256) {
    int f = i >> 7, c = i & 127;
    tile[c * 65 + f] = seq[(((size_t)(b * 64 + f)) * 512 + t) * 128 + c];
  }
  __syncthreads();
  for (int i = threadIdx.x; i < 128 * 64; i += 256) {
    int c = i >> 6, f = i & 63;
    out[(((size_t)(b * 128 + c)) * 512 + t) * 64 + f] = tile[c * 65 + f];
  }
}

// ---------------- layernorm over C=128, fp32 in -> bf16 out ----------------
__global__ __launch_bounds__(256) void ln_kernel(const float* __restrict__ in, const float* __restrict__ g,
                                                 const float* __restrict__ b, unsigned short* __restrict__ out) {
  int row = blockIdx.x * 4 + (threadIdx.x >> 6);
  int lane = threadIdx.x & 63;
  float2 v = ((const float2*)(in + (size_t)row * 128))[lane];
  float s = v.x + v.y, ss = v.x * v.x + v.y * v.y;
  #pragma unroll
  for (int off = 32; off > 0; off >>= 1) {
    s += __shfl_xor(s, off);
    ss += __shfl_xor(ss, off);
  }
  float mean = s * (1.f / 128.f);
  float var = ss * (1.f / 128.f) - mean * mean;
  float rs = rsqrtf(var + 1e-5f);
  float2 gg = ((const float2*)g)[lane];
  float2 bb = ((const float2*)b)[lane];
  float o0 = (v.x - mean) * rs * gg.x + bb.x;
  float o1 = (v.y - mean) * rs * gg.y + bb.y;
  unsigned int packed = ((unsigned int)f2bf(o1) << 16) | (unsigned int)f2bf(o0);
  ((unsigned int*)(out + (size_t)row * 128))[lane] = packed;
}

// ---------------- MFMA GEMM: out[m][n] (+)= sum_k A[m][k]*W[n][k] + bias[n] ----------------
// A bf16 [M][K] (M = gridDim.x*128), W bf16 [Ncols][K]. MODE 0: store bf16 (stride Ncols).
// MODE 1: outF[m*128+n] += v (fp32).
template <int K, int MODE>
__global__ __launch_bounds__(256) void gemm_mfma(const unsigned short* __restrict__ A,
                                                 const unsigned short* __restrict__ W,
                                                 const float* __restrict__ bias,
                                                 unsigned short* __restrict__ outB,
                                                 float* __restrict__ outF, int Ncols) {
  const int tid = threadIdx.x;
  const int wave = tid >> 6, lane = tid & 63;
  const int wy = wave >> 1, wx = wave & 1;
  const int lr = lane & 15, lq = lane >> 4;
  const int m0 = blockIdx.x * 128 + wy * 64;
  const int n0 = blockIdx.y * 128 + wx * 64;

  f32x4 acc[4][4];
  #pragma unroll
  for (int i = 0; i < 4; ++i)
    #pragma unroll
    for (int j = 0; j < 4; ++j) acc[i][j] = f32x4{0.f, 0.f, 0.f, 0.f};

  const short8 zfrag = short8{0, 0, 0, 0, 0, 0, 0, 0};

  #pragma unroll
  for (int kk = 0; kk < K; kk += 32) {
    short8 af[4], bfq[4];
    #pragma unroll
    for (int i = 0; i < 4; ++i)
      af[i] = *(const short8*)(A + (size_t)(m0 + i * 16 + lr) * K + kk + lq * 8);
    #pragma unroll
    for (int j = 0; j < 4; ++j) {
      int wr = n0 + j * 16 + lr;
      bfq[j] = (wr < Ncols) ? *(const short8*)(W + (size_t)wr * K + kk + lq * 8) : zfrag;
    }
    #pragma unroll
    for (int i = 0; i < 4; ++i)
      #pragma unroll
      for (int j = 0; j < 4; ++j)
        acc[i][j] = __builtin_amdgcn_mfma_f32_16x16x32_bf16(af[i], bfq[j], acc[i][j], 0, 0, 0);
  }

  #pragma unroll
  for (int j = 0; j < 4; ++j) {
    int col = n0 + j * 16 + lr;
    if (col < Ncols) {
      float bb = bias[col];
      #pragma unroll
      for (int i = 0; i < 4; ++i) {
        #pragma unroll
        for (int r = 0; r < 4; ++r) {
          int row = m0 + i * 16 + lq * 4 + r;
          float v = acc[i][j][r] + bb;
          if (MODE == 0)
            outB[(size_t)row * Ncols + col] = f2bf(v);
          else
            outF[(size_t)row * 128 + col] += v;
        }
      }
    }
  }
}

// ---------------- grouped GRU scan over T=512 — XOR-systolic register matvec ----------------
// 256 blocks x 64 threads (1 wave). Wave handles 2 chains: lanes 0..31 = chain 2*blk, lanes
// 32..63 = chain 2*blk+1 (same n). Lane owns hidden dim d = l&31.
//
// Round 7 post-mortem: gru = 649 cyc/step, VALU issue only ~80 cyc. The ~570 cyc stall is the
// per-step LDS h round-trip: ds_write(hnew) -> in-order DS pipe (queued behind the x-reads) ->
// 8x ds_read_b128 broadcast (~120+ cyc latency, single wave, nothing to hide it).
//
// Fix: keep h entirely in registers. Each lane needs all 32 h values; walk the XOR orbit
// c^k (k=0..15) with Gray-chained DPP shuffles (masks (k-1)^k in {1,3,7,15} — quad_perm and
// mirror patterns, all direction-symmetric so no rotate-direction ambiguity). The other
// 16-lane row's values ride in the second half of a packed f32x2 (one ds_swizzle xor16 per
// step, the only DS op left on the critical path). Weights are pre-permuted per-lane at init:
// wpk_g[k] = { w_g[d][rm*16 + (c^k)], w_g[d][(1-rm)*16 + (c^k)] } — identical arithmetic,
// reordered. x/sv values for all 8 steps are pre-read from the staged chunk into registers at
// chunk start (off the critical path). Matvec = 16 x {3 pk_fma + 2 mov_dpp}.
// Chunk staging/vmcnt machinery unchanged (6 DMAs + 8 stores/chunk -> counts 6/14/8).
__global__ __launch_bounds__(64, 1) void gru_kernel(const unsigned short* __restrict__ xp,
                                                    const float* __restrict__ whh,
                                                    const float* __restrict__ bhh,
                                                    float* __restrict__ seq) {
  const int l = threadIdx.x;
  const int half = l >> 5, d = l & 31;
  const int cc = l & 15, rm = (l >> 4) & 1;   // column / row within the chain's 32 lanes
  const int blk = blockIdx.x;           // 0..255
  const int chain = blk * 2 + half;     // chains 2b,2b+1 share n
  const int n = chain >> 2;
  const int g0 = (blk * 2) & 3;

  const float LOG2E = 1.4426950408889634f;
  const float T2LOG2E = 2.8853900817779268f;

  __shared__ __align__(16) unsigned char stage[2][6144];  // per buf: xp0 2K | xp1 2K | seq 2K

  // XOR-systolic packed weights: wpk_g[k] pairs (own-row, other-row) at h-index c^k.
  // Pre-scaled: r/z by log2e (sigmoid via exp2), n by 2*log2e (tanh via exp2).
  f32x2 wr2[16], wz2[16], wn2[16];
  #pragma unroll
  for (int k = 0; k < 16; ++k) {
    int jA = rm * 16 + (cc ^ k);
    int jB = (1 - rm) * 16 + (cc ^ k);
    wr2[k] = f32x2{whh[(size_t)d * 32 + jA] * LOG2E, whh[(size_t)d * 32 + jB] * LOG2E};
    wz2[k] = f32x2{whh[(size_t)(32 + d) * 32 + jA] * LOG2E, whh[(size_t)(32 + d) * 32 + jB] * LOG2E};
    wn2[k] = f32x2{whh[(size_t)(64 + d) * 32 + jA] * T2LOG2E, whh[(size_t)(64 + d) * 32 + jB] * T2LOG2E};
  }
  // Pins are LOAD-BEARING: they keep the loop free of remat vmem loads, which would corrupt
  // the vmcnt counts below.
  #pragma unroll
  for (int k = 0; k < 16; ++k)
    asm volatile("" : "+v"(wr2[k]), "+v"(wz2[k]), "+v"(wn2[k]));

  float br = bhh[d] * LOG2E, bz = bhh[32 + d] * LOG2E, bn = bhh[64 + d] * T2LOG2E;
  asm volatile("" : "+v"(br), "+v"(bz), "+v"(bn));

  // ---- per-lane DMA source addresses (unchanged layout) ----
  const char* xg = (const char*)xp;
  const size_t cb0 = ((size_t)n * 2048 + g0) * 192;
  const size_t cb1 = ((size_t)n * 2048 + g0 + 1) * 192;
  const int fa = l * 16;
  const int oxa = (fa / 192) * 768 + (fa % 192);
  const int fb = 1024 + l * 16;
  const int oxb = (fb / 192) * 768 + (fb % 192);
  const char* px0a = xg + cb0 + oxa;
  const char* px0b = xg + cb0 + oxb;
  const char* px1a = xg + cb1 + oxa;
  const char* px1b = xg + cb1 + oxb;
  const int osa = (l >> 4) * 512 + (l & 15) * 16;
  const size_t sqb0 = ((size_t)n * 512 * 128 + (size_t)g0 * 32) * 4;
  const char* psa = (const char*)seq + sqb0 + osa;
  const char* psb = psa + 2048;  // rows 4..7

  float* sb = seq + (size_t)n * 512 * 128 + g0 * 32 + l;  // per-lane output addr (t=0)

  // prologue: stage chunk 0 into buf 0
  glds16(px0a, stage[0] + 0);
  glds16(px0b, stage[0] + 1024);
  glds16(px1a, stage[0] + 2048);
  glds16(px1b, stage[0] + 3072);
  glds16(psa,  stage[0] + 4096);
  glds16(psb,  stage[0] + 5120);

  float hprev = 0.f;
  f32x2 h2cur = f32x2{0.f, 0.f};

  for (int c = 0; c < 64; ++c) {
    const int cur = c & 1;
    if (c < 63) {  // issue next chunk into the other buffer (stays in flight through compute)
      const size_t xo = (size_t)(c + 1) * 6144;
      const size_t so = (size_t)(c + 1) * 4096;
      unsigned char* nb = stage[cur ^ 1];
      glds16(px0a + xo, nb + 0);
      glds16(px0b + xo, nb + 1024);
      glds16(px1a + xo, nb + 2048);
      glds16(px1b + xo, nb + 3072);
      glds16(psa + so,  nb + 4096);
      glds16(psb + so,  nb + 5120);
    }
    __builtin_amdgcn_sched_barrier(0);
    if (c == 0)       asm volatile("s_waitcnt vmcnt(6)" ::: "memory");
    else if (c == 63) asm volatile("s_waitcnt vmcnt(8)" ::: "memory");
    else              asm volatile("s_waitcnt vmcnt(14)" ::: "memory");
    __builtin_amdgcn_sched_barrier(0);

    // pre-read this chunk's x/sv for all 8 steps (burst of DS reads, off the critical path)
    const unsigned char* scur = stage[cur];
    float pxr[8], pxz[8], pxn[8], psv[8];
    #pragma unroll
    for (int p = 0; p < 8; ++p) {
      const unsigned short* xrow = (const unsigned short*)(scur + half * 2048 + p * 192);
      pxr[p] = bf2f(xrow[d]) * LOG2E;
      pxz[p] = bf2f(xrow[32 + d]) * LOG2E;
      pxn[p] = bf2f(xrow[64 + d]) * T2LOG2E;
      psv[p] = *(const float*)(scur + 4096 + p * 256 + (l << 2));
    }

    #pragma unroll
    for (int p = 0; p < 8; ++p) {
      const int t = c * 8 + p;

      // matvec via XOR-systolic: state k holds h[c^k] in both row-halves (packed)
      f32x2 h2 = h2cur;
      f32x2 ar = f32x2{br, 0.f}, az = f32x2{bz, 0.f}, an = f32x2{bn, 0.f};
#define MV(K) ar += wr2[K] * h2; az += wz2[K] * h2; an += wn2[K] * h2;
      MV(0)  h2 = dpp2<0xB1>(h2);   // xor1
      MV(1)  h2 = dpp2<0x1B>(h2);   // xor3 -> state 2
      MV(2)  h2 = dpp2<0xB1>(h2);   // xor1 -> 3
      MV(3)  h2 = dpp2<0x141>(h2);  // xor7 -> 4
      MV(4)  h2 = dpp2<0xB1>(h2);   // -> 5
      MV(5)  h2 = dpp2<0x1B>(h2);   // -> 6
      MV(6)  h2 = dpp2<0xB1>(h2);   // -> 7
      MV(7)  h2 = dpp2<0x140>(h2);  // xor15 -> 8
      MV(8)  h2 = dpp2<0xB1>(h2);   // -> 9
      MV(9)  h2 = dpp2<0x1B>(h2);   // -> 10
      MV(10) h2 = dpp2<0xB1>(h2);   // -> 11
      MV(11) h2 = dpp2<0x141>(h2);  // -> 12
      MV(12) h2 = dpp2<0xB1>(h2);   // -> 13
      MV(13) h2 = dpp2<0x1B>(h2);   // -> 14
      MV(14) h2 = dpp2<0xB1>(h2);   // -> 15
      MV(15)
#undef MV
      float accr = ar.x + ar.y;   // = log2e * (whh_r . h + bhh_r)
      float accz = az.x + az.y;
      float accn = an.x + an.y;   // = 2*log2e * (whh_n . h + bhh_n)

      float r = __builtin_amdgcn_rcpf(1.f + __builtin_amdgcn_exp2f(-(pxr[p] + accr)));
      float z = __builtin_amdgcn_rcpf(1.f + __builtin_amdgcn_exp2f(-(pxz[p] + accz)));
      float e2 = __builtin_amdgcn_exp2f(pxn[p] + r * accn);
      float nn = 1.f - 2.f * __builtin_amdgcn_rcpf(e2 + 1.f);  // tanh, saturates at +/-1
      float hnew = z * (hprev - nn) + nn;
      hprev = hnew;

      // other-row copy for next step: lane l <-> l^16 (within each 32-lane chain half)
      int hb = __builtin_amdgcn_ds_swizzle(__float_as_int(hnew), 0x401F);
      h2cur = f32x2{hnew, __int_as_float(hb)};

      sb[(size_t)t * 128] = psv[p] + hnew;    // 64 lanes -> one coalesced 256 B store
    }
  }
}

// ---------------- windowed causal attention — MFMA flash (unchanged from round 7) ----------------
// grid (T/64=8, H=4, N=128), 256 threads = 4 waves; wave w owns q-tile [qbase+w*16, +16).
__global__ __launch_bounds__(256) void attn_kernel(const unsigned short* __restrict__ qkv,
                                                   unsigned short* __restrict__ outp) {
  const int qbase = blockIdx.x * 64;
  const int h = blockIdx.y;
  const int n = blockIdx.z;
  const int tid = threadIdx.x;
  const int w = tid >> 6, lane = tid & 63;
  const int lr = lane & 15, lq = lane >> 4;
  const int ws0 = max(0, qbase - 100);

  const int KROWS = 192;   // staged key rows (>= max window 164, rounded for DMA)
  const int VPITCH = 200;  // VT row pitch in u16 (breaks bank conflicts, 16B-aligned rows)
  const int PPITCH = 40;   // PL row pitch in u16

  __shared__ unsigned short KL[192 * 32];      // K rows [key][d]
  __shared__ unsigned short VT[32 * 200];      // V transposed [d][key]
  __shared__ unsigned short PL[4][16 * 40];    // per-wave P tile [q][k-chunk 32]
  __shared__ float LL[64];                     // per-wave row sums

  const char* qkvb = (const char*)qkv;
  const size_t rowb = ((size_t)(n * 512 + ws0)) * 768;  // window base row, bytes

  // Q A-frag: lane holds Q[q = wq0+lr][d = lq*8..+7] — one 16 B load
  const int wq0 = qbase + w * 16;
  short8 qfrag = *(const short8*)(qkvb + ((size_t)(n * 512 + wq0 + lr)) * 768 + h * 64 + lq * 16);

  // stage K rows via global_load_lds: chunk c (16 B) -> KL byte c*16; row c/4, piece c%4
  #pragma unroll
  for (int it = 0; it < 3; ++it) {
    int c = w * 192 + it * 64 + lane;
    const char* src = qkvb + rowb + (size_t)(c >> 2) * 768 + 256 + h * 64 + (size_t)(c & 3) * 16;
    glds16(src, (char*)KL + w * 3072 + it * 1024);
  }

  // stage V transposed: thread k reads V row, scatters 32 b16 into VT[d][k]
  if (tid < KROWS) {
    const unsigned int* vsrc = (const unsigned int*)(qkvb + rowb + (size_t)tid * 768 + 512 + h * 64);
    #pragma unroll
    for (int u = 0; u < 16; ++u) {
      unsigned int vv = vsrc[u];
      VT[(2 * u) * VPITCH + tid] = (unsigned short)(vv & 0xffff);
      VT[(2 * u + 1) * VPITCH + tid] = (unsigned short)(vv >> 16);
    }
  }
  __syncthreads();  // drains vmcnt (DMA) + lgkm (VT writes) for all waves

  const float SCL2 = 0.17677669529663687f * 1.4426950408889634f;  // 1/sqrt(32) * log2e
  const int lo = max(0, wq0 - 100) - ws0;  // first relevant key (rel), >= 0 always
  const int hi = wq0 + 15 - ws0;           // last relevant key (rel), <= 163
  const int kc0 = lo >> 5, kc1 = hi >> 5;  // 32-key chunks

  f32x4 oacc0 = f32x4{0.f, 0.f, 0.f, 0.f};
  f32x4 oacc1 = f32x4{0.f, 0.f, 0.f, 0.f};
  float lsum[4] = {0.f, 0.f, 0.f, 0.f};
  unsigned short* plw = PL[w];

  for (int kc = kc0; kc <= kc1; ++kc) {
    #pragma unroll
    for (int sub = 0; sub < 2; ++sub) {
      const int kt = kc * 2 + sub;
      short8 kfrag = *(const short8*)(KL + (kt * 16 + lr) * 32 + lq * 8);
      f32x4 s4 = __builtin_amdgcn_mfma_f32_16x16x32_bf16(qfrag, kfrag,
                                                         f32x4{0.f, 0.f, 0.f, 0.f}, 0, 0, 0);
      const int tk = ws0 + kt * 16 + lr;  // this lane's key column
      #pragma unroll
      for (int r = 0; r < 4; ++r) {
        const int tq = wq0 + lq * 4 + r;  // this reg's q row
        bool ok = (tk <= tq) && (tk + 100 >= tq);
        float p = ok ? __builtin_amdgcn_exp2f(s4[r] * SCL2) : 0.f;
        lsum[r] += p;
        plw[(lq * 4 + r) * PPITCH + sub * 16 + lr] = f2bf(p);
      }
    }
    // PV: same-wave DS in-order — reads see the writes above
    short8 pfrag = *(const short8*)(plw + lr * PPITCH + lq * 8);
    short8 vf0 = *(const short8*)(VT + lr * VPITCH + kc * 32 + lq * 8);
    short8 vf1 = *(const short8*)(VT + (16 + lr) * VPITCH + kc * 32 + lq * 8);
    oacc0 = __builtin_amdgcn_mfma_f32_16x16x32_bf16(vf0, pfrag, oacc0, 0, 0, 0);
    oacc1 = __builtin_amdgcn_mfma_f32_16x16x32_bf16(vf1, pfrag, oacc1, 0, 0, 0);
  }

  // row-sum butterfly over the 16 key-columns, then route to q=lr lanes via LDS
  #pragma unroll
  for (int r = 0; r < 4; ++r) {
    float v = lsum[r];
    v += __shfl_xor(v, 1); v += __shfl_xor(v, 2);
    v += __shfl_xor(v, 4); v += __shfl_xor(v, 8);
    lsum[r] = v;
  }
  if (lr == 0) {
    #pragma unroll
    for (int r = 0; r < 4; ++r) LL[w * 16 + lq * 4 + r] = lsum[r];
  }
  float rl = __builtin_amdgcn_rcpf(LL[w * 16 + lr]);  // same-wave DS in-order

  // O^T C-layout: lane holds O[d = dt*16 + lq*4 + r][q = lr] — 4 consecutive d -> dwordx2
  unsigned short* ob = outp + ((size_t)(n * 512 + wq0 + lr)) * 128 + h * 32 + lq * 4;
  {
    unsigned int w0 = ((unsigned int)f2bf(oacc0[1] * rl) << 16) | f2bf(oacc0[0] * rl);
    unsigned int w1 = ((unsigned int)f2bf(oacc0[3] * rl) << 16) | f2bf(oacc0[2] * rl);
    uint2 pk0; pk0.x = w0; pk0.y = w1;
    *(uint2*)ob = pk0;
    unsigned int w2 = ((unsigned int)f2bf(oacc1[1] * rl) << 16) | f2bf(oacc1[0] * rl);
    unsigned int w3 = ((unsigned int)f2bf(oacc1[3] * rl) << 16) | f2bf(oacc1[2] * rl);
    uint2 pk1; pk1.x = w2; pk1.y = w3;
    *(uint2*)(ob + 16) = pk1;
  }
}

// ---------------- host launcher ----------------
extern "C" void kernel_launch(void* const* d_in, const int* in_sizes, int n_in,
                              void* d_out, int out_size, void* d_ws, size_t ws_size,
                              hipStream_t stream) {
  const float* x      = (const float*)d_in[0];
  const float* ln1_g  = (const float*)d_in[1];
  const float* ln1_b  = (const float*)d_in[2];
  const float* wih    = (const float*)d_in[3];
  const float* whh    = (const float*)d_in[4];
  const float* bih    = (const float*)d_in[5];
  const float* bhh    = (const float*)d_in[6];
  const float* ln2_g  = (const float*)d_in[7];
  const float* ln2_b  = (const float*)d_in[8];
  const float* inw    = (const float*)d_in[9];
  const float* inb    = (const float*)d_in[10];
  const float* outw   = (const float*)d_in[11];
  const float* outb   = (const float*)d_in[12];

  char* ws = (char*)d_ws;
  float*          seq   = (float*)ws;                             // 33,554,432 B
  unsigned short* tmpb  = (unsigned short*)(ws + 33554432);       // 16,777,216 B
  unsigned short* big   = (unsigned short*)(ws + 50331648);       // 50,331,648 B
  unsigned short* wih_b = (unsigned short*)(ws + 100663296);      // 3072 elems
  unsigned short* inw_b = wih_b + 3072;                           // 49152 elems
  unsigned short* outw_b = inw_b + 49152;                         // 16384 elems

  cvt_kernel<<<12, 256, 0, stream>>>(wih, wih_b, 3072);
  cvt_kernel<<<192, 256, 0, stream>>>(inw, inw_b, 49152);
  cvt_kernel<<<64, 256, 0, stream>>>(outw, outw_b, 16384);

  // x -> seq (residual stream)
  transpose_in_kernel<<<1024, 256, 0, stream>>>(x, seq);

  // ln1 -> tmpb (bf16), grouped view [262144][32]
  ln_kernel<<<16384, 256, 0, stream>>>(seq, ln1_g, ln1_b, tmpb);

  // GRU input projection: [262144][32] x [96][32]^T -> big [(n,t,g)][96]
  gemm_mfma<32, 0><<<dim3(2048, 1), 256, 0, stream>>>(tmpb, wih_b, bih, big, nullptr, 96);

  // GRU scan, seq += h_t  (single-wave blocks, 2 chains/wave)
  gru_kernel<<<256, 64, 0, stream>>>(big, whh, bhh, seq);

  // ln2 -> tmpb
  ln_kernel<<<16384, 256, 0, stream>>>(seq, ln2_g, ln2_b, tmpb);

  // QKV projection: [65536][128] x [384][128]^T -> big [65536][384]
  gemm_mfma<128, 0><<<dim3(512, 3), 256, 0, stream>>>(tmpb, inw_b, inb, big, nullptr, 384);

  // attention -> tmpb (bf16)
  attn_kernel<<<dim3(8, 4, 128), 256, 0, stream>>>(big, tmpb);

  // out projection, seq += attn @ Wo^T + bo
  gemm_mfma<128, 1><<<dim3(512, 1), 256, 0, stream>>>(tmpb, outw_b, outb, nullptr, seq, 128);

  // seq -> d_out
  transpose_out_kernel<<<1024, 256, 0, stream>>>(seq, (float*)d_out);
}